// Round 1
// baseline (711.041 us; speedup 1.0000x reference)
//
#include <hip/hip_runtime.h>

typedef __attribute__((ext_vector_type(4))) float f32x4;
typedef __attribute__((ext_vector_type(8))) __bf16 bf16x8;
typedef __attribute__((ext_vector_type(8))) unsigned short us8;
typedef unsigned short u16;

#define SSILU_SCALE (1.0f / 0.6f)
#define INV_SQRT2 0.70710678118654752f

__device__ __forceinline__ u16 f2bf(float f) {
    union { float f; unsigned int u; } v; v.f = f;
    unsigned int r = (v.u + 0x7fffu + ((v.u >> 16) & 1u)) >> 16;
    return (u16)r;
}
__device__ __forceinline__ float bf2f(u16 h) {
    union { unsigned int u; float f; } v; v.u = ((unsigned int)h) << 16;
    return v.f;
}
__device__ __forceinline__ float ssilu(float x) {
    return x / (1.0f + __expf(-x)) * SSILU_SCALE;
}

// ---------------------------------------------------------------------------
// prep: transpose-convert weights fp32 -> bf16 Wt[N][K]; zero d_out.
// Wt_in : [256][1280]  (from W_in [1280][256])
// Wt_r  : 4 x [256][256]
// ---------------------------------------------------------------------------
__global__ __launch_bounds__(256) void prep_kernel(
    const float* __restrict__ Win, const float* __restrict__ W1a,
    const float* __restrict__ W1b, const float* __restrict__ W2a,
    const float* __restrict__ W2b, u16* __restrict__ WtIn,
    u16* __restrict__ WtR, float* __restrict__ out, int outN) {
    int i = blockIdx.x * 256 + threadIdx.x;
    if (i < 256 * 1280) {
        int n = i / 1280, k = i % 1280;
        WtIn[i] = f2bf(Win[k * 256 + n]);
        return;
    }
    int j = i - 256 * 1280;
    if (j < 4 * 65536) {
        int m = j >> 16, r = j & 65535;
        int n = r >> 8, k = r & 255;
        const float* W = (m == 0) ? W1a : (m == 1) ? W1b : (m == 2) ? W2a : W2b;
        WtR[j] = f2bf(W[k * 256 + n]);
        return;
    }
    int z = j - 4 * 65536;
    if (z < outN) out[z] = 0.0f;
}

// ---------------------------------------------------------------------------
// gemm1: h = ssilu(x_cat @ W_in), A fp32 [E][1280], Wt bf16 [256][1280],
// h bf16 [E][256].  Block: 64 rows x 256 cols, 4 waves (wave w -> cols 64w..).
// ---------------------------------------------------------------------------
__global__ __launch_bounds__(256) void gemm1_kernel(
    const float* __restrict__ A, const u16* __restrict__ Wt,
    u16* __restrict__ H) {
    __shared__ u16 As[64 * 64];    // [row][k] swizzled, 128B rows
    __shared__ u16 Bs[256 * 64];   // [col][k] swizzled, 128B rows
    const int t = threadIdx.x, w = t >> 6, l = t & 63;
    const int lo = l & 15, hi = l >> 4;
    const long rowbase = (long)blockIdx.x * 64;
    char* AsB = (char*)As;
    char* BsB = (char*)Bs;

    f32x4 acc[4][4];
#pragma unroll
    for (int m = 0; m < 4; m++)
#pragma unroll
        for (int n = 0; n < 4; n++) acc[m][n] = (f32x4){0.f, 0.f, 0.f, 0.f};

    for (int kb = 0; kb < 1280; kb += 64) {
        // stage A: fp32 -> bf16, 64x64, 2 chunks of 8 elems per thread
#pragma unroll
        for (int c = 0; c < 2; ++c) {
            int c2 = t + c * 256;
            int r = c2 >> 3, k8 = (c2 & 7) * 8;
            const float* s = A + (rowbase + r) * 1280 + kb + k8;
            float4 v0 = *(const float4*)s;
            float4 v1 = *(const float4*)(s + 4);
            us8 p;
            p[0] = f2bf(v0.x); p[1] = f2bf(v0.y); p[2] = f2bf(v0.z); p[3] = f2bf(v0.w);
            p[4] = f2bf(v1.x); p[5] = f2bf(v1.y); p[6] = f2bf(v1.z); p[7] = f2bf(v1.w);
            *(us8*)(AsB + r * 128 + ((k8 * 2) ^ ((r & 7) << 4))) = p;
        }
        // stage B: Wt[col][kb..kb+64), 256x64 bf16, 8 chunks per thread
#pragma unroll
        for (int c = 0; c < 8; ++c) {
            int c2 = t + c * 256;
            int nc = c2 >> 3, k8 = (c2 & 7) * 8;
            us8 p = *(const us8*)(Wt + (size_t)nc * 1280 + kb + k8);
            *(us8*)(BsB + nc * 128 + ((k8 * 2) ^ ((nc & 7) << 4))) = p;
        }
        __syncthreads();
#pragma unroll
        for (int kk = 0; kk < 2; ++kk) {
            int kbyte = kk * 64 + hi * 16;
            bf16x8 af[4], bv[4];
#pragma unroll
            for (int m = 0; m < 4; m++) {
                int r = m * 16 + lo;
                af[m] = __builtin_bit_cast(bf16x8,
                    *(const us8*)(AsB + r * 128 + (kbyte ^ ((r & 7) << 4))));
            }
#pragma unroll
            for (int n = 0; n < 4; n++) {
                int cc = w * 64 + n * 16 + lo;
                bv[n] = __builtin_bit_cast(bf16x8,
                    *(const us8*)(BsB + cc * 128 + (kbyte ^ ((cc & 7) << 4))));
            }
#pragma unroll
            for (int m = 0; m < 4; m++)
#pragma unroll
                for (int n = 0; n < 4; n++)
                    acc[m][n] = __builtin_amdgcn_mfma_f32_16x16x32_bf16(
                        af[m], bv[n], acc[m][n], 0, 0, 0);
        }
        __syncthreads();
    }
    // epilogue: ssilu, store bf16
#pragma unroll
    for (int m = 0; m < 4; m++)
#pragma unroll
        for (int n = 0; n < 4; n++)
#pragma unroll
            for (int j = 0; j < 4; j++) {
                float v = ssilu(acc[m][n][j]);
                long r = rowbase + m * 16 + hi * 4 + j;
                int cc = w * 64 + n * 16 + lo;
                H[r * 256 + cc] = f2bf(v);
            }
}

// ---------------------------------------------------------------------------
// resid: fused 2 residual blocks + W_out dot + edge_vec scale + scatter-add.
// Block: 64 rows. x tile in swizzled LDS (bf16). W read from global (L2).
// ---------------------------------------------------------------------------
__device__ __forceinline__ void gemm_lds(const char* AB, const u16* __restrict__ Wg,
                                         int w, int lo, int hi, f32x4 acc[4][4]) {
#pragma unroll
    for (int m = 0; m < 4; m++)
#pragma unroll
        for (int n = 0; n < 4; n++) acc[m][n] = (f32x4){0.f, 0.f, 0.f, 0.f};
#pragma unroll
    for (int kk = 0; kk < 8; ++kk) {
        int kbyte = kk * 64 + hi * 16;
        bf16x8 af[4], bv[4];
#pragma unroll
        for (int m = 0; m < 4; m++) {
            int r = m * 16 + lo;
            af[m] = __builtin_bit_cast(bf16x8,
                *(const us8*)(AB + r * 512 + (kbyte ^ ((r & 7) << 4))));
        }
#pragma unroll
        for (int n = 0; n < 4; n++) {
            int cc = w * 64 + n * 16 + lo;
            bv[n] = __builtin_bit_cast(bf16x8,
                *(const us8*)(Wg + (size_t)cc * 256 + kk * 32 + hi * 8));
        }
#pragma unroll
        for (int m = 0; m < 4; m++)
#pragma unroll
            for (int n = 0; n < 4; n++)
                acc[m][n] = __builtin_amdgcn_mfma_f32_16x16x32_bf16(
                    af[m], bv[n], acc[m][n], 0, 0, 0);
    }
}

__global__ __launch_bounds__(256) void resid_kernel(
    const u16* __restrict__ H, const u16* __restrict__ WtR,
    const float* __restrict__ Wout, const float* __restrict__ evec,
    const int* __restrict__ eidx, float* __restrict__ out) {
    __shared__ u16 xb[64 * 256];   // [row][col] swizzled, 512B rows
    __shared__ u16 tb[64 * 256];
    __shared__ float fpart[4][64];
    const int t = threadIdx.x, w = t >> 6, l = t & 63;
    const int lo = l & 15, hi = l >> 4;
    const long rowbase = (long)blockIdx.x * 64;
    char* xbB = (char*)xb;
    char* tbB = (char*)tb;

    // load x tile from H (bf16) into swizzled LDS
#pragma unroll
    for (int c = 0; c < 8; ++c) {
        int c2 = t + c * 256;
        int r = c2 >> 5, k8 = (c2 & 31) * 8;
        us8 p = *(const us8*)(H + (rowbase + r) * 256 + k8);
        *(us8*)(xbB + r * 512 + ((k8 * 2) ^ ((r & 7) << 4))) = p;
    }
    __syncthreads();

    f32x4 acc[4][4];

    // ---- G1: t1 = ssilu(x @ W1a) -> tb
    gemm_lds(xbB, WtR + 0 * 65536, w, lo, hi, acc);
#pragma unroll
    for (int m = 0; m < 4; m++)
#pragma unroll
        for (int n = 0; n < 4; n++)
#pragma unroll
            for (int j = 0; j < 4; j++) {
                int r = m * 16 + hi * 4 + j;
                int cc = w * 64 + n * 16 + lo;
                *(u16*)(tbB + r * 512 + ((cc * 2) ^ ((r & 7) << 4))) =
                    f2bf(ssilu(acc[m][n][j]));
            }
    __syncthreads();

    // ---- G2: x = (x + ssilu(t1 @ W1b)) * INV_SQRT2 -> xb
    gemm_lds(tbB, WtR + 1 * 65536, w, lo, hi, acc);
#pragma unroll
    for (int m = 0; m < 4; m++)
#pragma unroll
        for (int n = 0; n < 4; n++)
#pragma unroll
            for (int j = 0; j < 4; j++) {
                int r = m * 16 + hi * 4 + j;
                int cc = w * 64 + n * 16 + lo;
                char* p = xbB + r * 512 + ((cc * 2) ^ ((r & 7) << 4));
                float xn = (bf2f(*(u16*)p) + ssilu(acc[m][n][j])) * INV_SQRT2;
                *(u16*)p = f2bf(xn);
            }
    __syncthreads();

    // ---- G3: t1 = ssilu(x @ W2a) -> tb
    gemm_lds(xbB, WtR + 2 * 65536, w, lo, hi, acc);
#pragma unroll
    for (int m = 0; m < 4; m++)
#pragma unroll
        for (int n = 0; n < 4; n++)
#pragma unroll
            for (int j = 0; j < 4; j++) {
                int r = m * 16 + hi * 4 + j;
                int cc = w * 64 + n * 16 + lo;
                *(u16*)(tbB + r * 512 + ((cc * 2) ^ ((r & 7) << 4))) =
                    f2bf(ssilu(acc[m][n][j]));
            }
    __syncthreads();

    // ---- G4: x_final = (x + ssilu(t1 @ W2b)) * INV_SQRT2 (kept fp32 in regs)
    gemm_lds(tbB, WtR + 3 * 65536, w, lo, hi, acc);
    float wo[4];
#pragma unroll
    for (int n = 0; n < 4; n++) wo[n] = Wout[w * 64 + n * 16 + lo];

    float part[4][4];
#pragma unroll
    for (int m = 0; m < 4; m++)
#pragma unroll
        for (int j = 0; j < 4; j++) part[m][j] = 0.f;
#pragma unroll
    for (int m = 0; m < 4; m++)
#pragma unroll
        for (int n = 0; n < 4; n++)
#pragma unroll
            for (int j = 0; j < 4; j++) {
                int r = m * 16 + hi * 4 + j;
                int cc = w * 64 + n * 16 + lo;
                const char* p = xbB + r * 512 + ((cc * 2) ^ ((r & 7) << 4));
                float xf = (bf2f(*(const u16*)p) + ssilu(acc[m][n][j])) * INV_SQRT2;
                part[m][j] += xf * wo[n];
            }
    // reduce over 16 cols (lanes sharing l>>4)
#pragma unroll
    for (int m = 0; m < 4; m++)
#pragma unroll
        for (int j = 0; j < 4; j++) {
            float v = part[m][j];
            v += __shfl_xor(v, 1);
            v += __shfl_xor(v, 2);
            v += __shfl_xor(v, 4);
            v += __shfl_xor(v, 8);
            if (lo == 0) fpart[w][m * 16 + hi * 4 + j] = v;
        }
    __syncthreads();

    if (t < 64) {
        int r = t;
        float F = fpart[0][r] + fpart[1][r] + fpart[2][r] + fpart[3][r];
        long e = rowbase + r;
        float vx = evec[e * 3 + 0], vy = evec[e * 3 + 1], vz = evec[e * 3 + 2];
        int a = eidx[e];
        atomicAdd(&out[a * 3 + 0], F * vx);
        atomicAdd(&out[a * 3 + 1], F * vy);
        atomicAdd(&out[a * 3 + 2], F * vz);
    }
}

extern "C" void kernel_launch(void* const* d_in, const int* in_sizes, int n_in,
                              void* d_out, int out_size, void* d_ws, size_t ws_size,
                              hipStream_t stream) {
    const float* x_cat = (const float*)d_in[0];
    const float* evec  = (const float*)d_in[1];
    const int*   eidx  = (const int*)d_in[2];
    const float* Win   = (const float*)d_in[3];
    const float* W1a   = (const float*)d_in[4];
    const float* W1b   = (const float*)d_in[5];
    const float* W2a   = (const float*)d_in[6];
    const float* W2b   = (const float*)d_in[7];
    const float* Wout  = (const float*)d_in[8];
    float* out = (float*)d_out;
    const int E = in_sizes[1] / 3;  // 200000

    size_t hBytes = (size_t)E * 256 * sizeof(u16);
    u16* H    = (u16*)d_ws;
    u16* WtIn = (u16*)((char*)d_ws + hBytes);
    u16* WtR  = WtIn + 256 * 1280;

    int prepN = 256 * 1280 + 4 * 65536 + out_size;
    prep_kernel<<<(prepN + 255) / 256, 256, 0, stream>>>(
        Win, W1a, W1b, W2a, W2b, WtIn, WtR, out, out_size);
    gemm1_kernel<<<E / 64, 256, 0, stream>>>(x_cat, WtIn, H);
    resid_kernel<<<E / 64, 256, 0, stream>>>(H, WtR, Wout, evec, eidx, out);
}